// Round 14
// baseline (296.625 us; speedup 1.0000x reference)
//
#include <hip/hip_runtime.h>
#include <math.h>

#pragma clang fp contract(off)

#define NPTS 4096
#define PTS  32768
#define ROWS 163840   // PTS * 5
#define QN   4        // candidate slices per batch
#define QLEN 1024     // NPTS / QN
#define SLOTS 8       // packed top-k slots per slice (and global survivors)

// LAPACK single-precision machine constants (gfortran/IEEE):
#define EPS_L   5.9604644775390625e-8f    // 2^-24  SLAMCH('E')
#define EPS2_L  3.5527136788005009e-15f   // 2^-48
#define SAFMIN_L 1.1754943508222875e-38f  // 2^-126

// Round-to-nearest, non-contractible f32 ops (file pragma disables fusion).
__device__ __forceinline__ float frn_mul(float a, float b) { float r = a * b; return r; }
__device__ __forceinline__ float frn_add(float a, float b) { float r = a + b; return r; }
__device__ __forceinline__ float frn_sub(float a, float b) { float r = a - b; return r; }
__device__ __forceinline__ float frn_div(float a, float b) { float r = a / b; return r; }

__device__ __forceinline__ float ref_sq(float x0, float x1) {
  return frn_add(frn_mul(x0, x0), frn_mul(x1, x1));
}
// dist_sq[n,m] = fl( fl(sq_n + sq_m) - 2*dot ), dot = fma(ny*my, fl(nx*mx)).
__device__ __forceinline__ float ref_key(float nx, float ny, float sqn,
                                         float mx, float my, float sqm) {
  float dot = fmaf(ny, my, frn_mul(nx, mx));
  float s = frn_add(sqn, sqm);
  return fmaf(-2.0f, dot, s);
}

// ---------------------------------------------------------------------------
// Weight transpose prep, zero-padded K stride: wt[j*Kp + i] = (i<K)? w[i*N+j]:0
// ---------------------------------------------------------------------------
__global__ __launch_bounds__(256) void prep_w(
    const float* __restrict__ lw1, const float* __restrict__ lw2, const float* __restrict__ lw3,
    const float* __restrict__ cw1, const float* __restrict__ cw2,
    const float* __restrict__ tw1, const float* __restrict__ tw2,
    float* __restrict__ wt) {
  const int Ks[7]   = {2, 64, 128, 66, 128, 64, 128};
  const int Kp[7]   = {2, 64, 128, 80, 128, 64, 128};
  const int Ns[7]   = {64, 128, 64, 128, 128, 128, 128};
  const int offs[7] = {0, 128, 8320, 16512, 26752, 43136, 51328};
  const float* srcs[7] = {lw1, lw2, lw3, cw1, cw2, tw1, tw2};
  int b = blockIdx.x;
  const float* src = srcs[b];
  float* dst = wt + offs[b];
  int K = Ks[b], KP = Kp[b], N = Ns[b];
  for (int e = threadIdx.x; e < KP * N; e += 256) {
    int j = e / KP, i = e - j * KP;
    dst[e] = (i < K) ? src[i * N + j] : 0.0f;
  }
}

// ---------------------------------------------------------------------------
// kNN scan (brute force): 512 blocks = 128 point-groups of 256 x 4
// candidate-slices of 1024 (QN 8->4 rebalance: flush work ~log(QLEN) while
// slices/point halve; also halves merge_geom's gather). 24 KB LDS -> 2
// blocks/CU; 512 blocks = exactly 2 rounds of 256 CUs. Threshold-filtered
// top-8, unroll-4, unconditional buffered append (failing write lands in
// slot cnt; only promoted when a passing value overwrites it). Flush-check
// every 4 candidates, cnt>=13 (start-of-group cnt<=12, +4 -> slots <= 15).
// Packed value = (bits(dist)&0xFFFFF000)|idx (dist >= 0 u32-monotone).
// Monotone threshold T => no true top-8 element dropped (values distinct by
// idx); exact ref-key re-rank happens in merge_geom.
// ---------------------------------------------------------------------------
__device__ __forceinline__ void cand_step(float mex, float mey, float cx, float cy,
                                          unsigned int idx, unsigned int T,
                                          unsigned int* sbuf, int t,
                                          unsigned int& cnt) {
  float dx = mex - cx, dy = mey - cy;
  float dist = fmaf(dy, dy, dx * dx);
  unsigned int v = (__float_as_uint(dist) & 0xFFFFF000u) | idx;
  sbuf[cnt * 256 + t] = v;
  cnt += (v < T) ? 1u : 0u;
}

__global__ __launch_bounds__(256) void knn_scan(const float* __restrict__ x,
                                                unsigned int* __restrict__ ipart) {
  __shared__ float2 cand[QLEN];            // 8 KB
  __shared__ unsigned int sbuf[16 * 256];  // 16 KB survivor buffer
  int bx = blockIdx.x;
  int q = bx & (QN - 1);
  int pg = bx >> 2;              // 0..127 point-groups of 256
  int batch = pg >> 4;           // 16 groups per batch
  const float* xb = x + (size_t)batch * NPTS * 2;
  int c0 = q * QLEN;
  for (int i = threadIdx.x; i < QLEN; i += 256)
    cand[i] = ((const float2*)xb)[c0 + i];
  __syncthreads();
  int t = threadIdx.x;
  int p = pg * 256 + t;
  float2 me = ((const float2*)x)[p];
  unsigned int d[SLOTS];
#pragma unroll
  for (int s = 0; s < SLOTS; s++) d[s] = 0xFFFFFFFFu;
  unsigned int T = 0xFFFFFFFFu;
  unsigned int cnt = 0;
  for (int mm = 0; mm < QLEN / 4; mm++) {
    float4 c01 = ((const float4*)cand)[2 * mm];
    float4 c23 = ((const float4*)cand)[2 * mm + 1];
    unsigned int idx0 = (unsigned int)(c0 + 4 * mm);
    cand_step(me.x, me.y, c01.x, c01.y, idx0 + 0u, T, sbuf, t, cnt);
    cand_step(me.x, me.y, c01.z, c01.w, idx0 + 1u, T, sbuf, t, cnt);
    cand_step(me.x, me.y, c23.x, c23.y, idx0 + 2u, T, sbuf, t, cnt);
    cand_step(me.x, me.y, c23.z, c23.w, idx0 + 3u, T, sbuf, t, cnt);
    if (__any((int)(cnt >= 13u))) {
#pragma unroll
      for (int j = 0; j < 16; j++) {
        unsigned int u = ((unsigned)j < cnt) ? sbuf[j * 256 + t] : 0xFFFFFFFFu;
#pragma unroll
        for (int s = 0; s < SLOTS; s++) {
          unsigned int lo = min(u, d[s]);
          unsigned int hi = max(u, d[s]);
          d[s] = lo; u = hi;
        }
      }
      cnt = 0;
      T = d[SLOTS - 1];
    }
  }
  // final flush of residual buffer entries
#pragma unroll
  for (int j = 0; j < 16; j++) {
    unsigned int u = ((unsigned)j < cnt) ? sbuf[j * 256 + t] : 0xFFFFFFFFu;
#pragma unroll
    for (int s = 0; s < SLOTS; s++) {
      unsigned int lo = min(u, d[s]);
      unsigned int hi = max(u, d[s]);
      d[s] = lo; u = hi;
    }
  }
#pragma unroll
  for (int s = 0; s < SLOTS; s++)
    ipart[((size_t)(q * SLOTS + s)) * PTS + p] = d[s];
}

#define CAS(a, b) { unsigned int _l = min(a, b), _h = max(a, b); a = _l; b = _h; }

// ---------------------------------------------------------------------------
// Merge + geometry. BURST-loads all QN*8=32 packed survivors into registers
// (32 independent loads in flight -> ~1 memory round-trip instead of 4
// dependent rounds; this kernel runs at only 2 waves/CU so every serialized
// round costs full latency), then tree-merges the 4 sorted lists (bitonic
// merge-of-two-sorted-8s, HW-proven) -> packed top-8 -> exact (f32 ref key,
// idx) lex re-rank -> reference top-5 -> covariance -> ssteqr/SLAEV2
// replica -> angle/axes + interleaved lcc (float2). Also writes the
// x-passthrough rows (0,1) of lftx and zero-fills padding rows 66..79.
// 256 blocks x 128 threads.
// ---------------------------------------------------------------------------
__device__ __forceinline__ void merge8(unsigned int* g, const unsigned int* B) {
  unsigned int w[SLOTS];
#pragma unroll
  for (int s = 0; s < SLOTS; s++) w[s] = min(g[s], B[SLOTS - 1 - s]);
  CAS(w[0], w[4]); CAS(w[1], w[5]); CAS(w[2], w[6]); CAS(w[3], w[7]);
  CAS(w[0], w[2]); CAS(w[1], w[3]); CAS(w[4], w[6]); CAS(w[5], w[7]);
  CAS(w[0], w[1]); CAS(w[2], w[3]); CAS(w[4], w[5]); CAS(w[6], w[7]);
#pragma unroll
  for (int s = 0; s < SLOTS; s++) g[s] = w[s];
}

__global__ __launch_bounds__(128) void merge_geom(const float* __restrict__ x,
    const unsigned int* __restrict__ ipart,
    float2* __restrict__ lcct2,
    float* __restrict__ angle_out, float2* __restrict__ axes_out,
    float* __restrict__ lftx) {
  int p = blockIdx.x * 128 + threadIdx.x;
  int batch = p >> 12;
  const float2* xb = (const float2*)(x + (size_t)batch * NPTS * 2);
  float2 me = ((const float2*)x)[p];
  lftx[p] = me.x;
  lftx[PTS + p] = me.y;
#pragma unroll
  for (int r = 66; r < 80; r++) lftx[(size_t)r * PTS + p] = 0.0f;
  float sqn = ref_sq(me.x, me.y);

  // Burst gather: all 32 loads issued before any use.
  unsigned int raw[QN][SLOTS];
#pragma unroll
  for (int qs = 0; qs < QN; qs++)
#pragma unroll
    for (int s = 0; s < SLOTS; s++)
      raw[qs][s] = ipart[(size_t)(qs * SLOTS + s) * PTS + p];
  // Tree-merge (each list sorted ascending; values distinct by idx).
  merge8(raw[0], raw[1]);
  merge8(raw[2], raw[3]);
  merge8(raw[0], raw[2]);
  unsigned int* g = raw[0];

  float dk[5]; int id[5];
#pragma unroll
  for (int s = 0; s < 5; s++) { dk[s] = 3.0e38f; id[s] = 0x7fffffff; }
#pragma unroll
  for (int s8 = 0; s8 < SLOTS; s8++) {
    int ci = (int)(g[s8] & 0xFFFu);
    float2 c = xb[ci];
    float key = ref_key(me.x, me.y, sqn, c.x, c.y, ref_sq(c.x, c.y));
    float v = key; int vi = ci;
#pragma unroll
    for (int s = 0; s < 5; s++) {
      bool lt = (v < dk[s]) || (v == dk[s] && vi < id[s]);
      float tv = dk[s]; int ti = id[s];
      if (lt) { dk[s] = v; id[s] = vi; v = tv; vi = ti; }
    }
  }
  float rx[5], ry[5];
  float sx = 0.f, sy = 0.f;
#pragma unroll
  for (int k = 0; k < 5; k++) {
    float2 nb = xb[id[k]];
    rx[k] = frn_sub(nb.x, me.x); ry[k] = frn_sub(nb.y, me.y);
    sx = frn_add(sx, rx[k]); sy = frn_add(sy, ry[k]);
  }
  float mx = frn_div(sx, 5.0f), my = frn_div(sy, 5.0f);
  float c00 = 0.f, c01 = 0.f, c11 = 0.f;
#pragma unroll
  for (int k = 0; k < 5; k++) {
    rx[k] = frn_sub(rx[k], mx); ry[k] = frn_sub(ry[k], my);
    c00 = frn_add(c00, frn_mul(rx[k], rx[k]));
    c01 = frn_add(c01, frn_mul(rx[k], ry[k]));
    c11 = frn_add(c11, frn_mul(ry[k], ry[k]));
  }
  c00 = frn_div(c00, 4.0f); c01 = frn_div(c01, 4.0f); c11 = frn_div(c11, 4.0f);
  float A = frn_add(c00, 1e-6f), Bv = c01, C = frn_add(c11, 1e-6f);

  // ---- ssteqr 2x2 replica ----
  float absA = fabsf(A), absC = fabsf(C), absB = fabsf(Bv);
  float thr = frn_mul(frn_mul(sqrtf(absA), sqrtf(absC)), EPS_L);
  bool diag = (absB == 0.f) || (absB <= thr);
  if (!diag) {
    bool qr = (absC < absA);
    float b2 = frn_mul(absB, absB);
    float t = qr ? frn_add(frn_mul(frn_mul(EPS2_L, absC), absA), SAFMIN_L)
                 : frn_add(frn_mul(frn_mul(EPS2_L, absA), absC), SAFMIN_L);
    if (b2 <= t) diag = true;
  }
  float e1, e2, v00, v10, v01, v11;
  if (diag) {
    if (C < A) { e1 = C; e2 = A; v00 = 0.f; v10 = 1.f; v01 = 1.f; v11 = 0.f; }
    else       { e1 = A; e2 = C; v00 = 1.f; v10 = 0.f; v01 = 0.f; v11 = 1.f; }
  } else {
    // ---- SLAEV2 replica ----
    float sm = frn_add(A, C), df = frn_sub(A, C);
    float adf = fabsf(df), tb = frn_add(Bv, Bv), ab = fabsf(tb);
    float rt;
    if (adf > ab) {
      float r = frn_div(ab, adf);
      rt = frn_mul(adf, sqrtf(frn_add(1.0f, frn_mul(r, r))));
    } else if (adf < ab) {
      float r = frn_div(adf, ab);
      rt = frn_mul(ab, sqrtf(frn_add(1.0f, frn_mul(r, r))));
    } else {
      rt = frn_mul(ab, sqrtf(2.0f));
    }
    float acmx, acmn;
    if (absA > absC) { acmx = A; acmn = C; } else { acmx = C; acmn = A; }
    float rt1, rt2; int sgn1;
    if (sm < 0.f) {
      rt1 = frn_mul(0.5f, frn_sub(sm, rt)); sgn1 = -1;
      rt2 = frn_sub(frn_mul(frn_div(acmx, rt1), acmn), frn_mul(frn_div(Bv, rt1), Bv));
    } else if (sm > 0.f) {
      rt1 = frn_mul(0.5f, frn_add(sm, rt)); sgn1 = 1;
      rt2 = frn_sub(frn_mul(frn_div(acmx, rt1), acmn), frn_mul(frn_div(Bv, rt1), Bv));
    } else {
      rt1 = frn_mul(0.5f, rt); rt2 = frn_mul(-0.5f, rt); sgn1 = 1;
    }
    float cs, cs1, sn1; int sgn2;
    if (df >= 0.f) { cs = frn_add(df, rt); sgn2 = 1; }
    else           { cs = frn_sub(df, rt); sgn2 = -1; }
    float acs = fabsf(cs);
    if (acs > ab) {
      float ct = frn_div(-tb, cs);
      sn1 = frn_div(1.0f, sqrtf(frn_add(1.0f, frn_mul(ct, ct))));
      cs1 = frn_mul(ct, sn1);
    } else {
      if (ab == 0.f) { cs1 = 1.0f; sn1 = 0.0f; }
      else {
        float tn = frn_div(-cs, tb);
        cs1 = frn_div(1.0f, sqrtf(frn_add(1.0f, frn_mul(tn, tn))));
        sn1 = frn_mul(tn, cs1);
      }
    }
    if (sgn1 == sgn2) { float t = cs1; cs1 = -sn1; sn1 = t; }
    if (rt2 < rt1) { e1 = rt2; e2 = rt1; v00 = -sn1; v10 = cs1; v01 = cs1;  v11 = sn1; }
    else           { e1 = rt1; e2 = rt2; v00 = cs1;  v10 = sn1; v01 = -sn1; v11 = cs1; }
  }

  angle_out[p] = atan2f(v11, v01);
  float aM = sqrtf(fmaxf(e2, 1e-6f));
  float am = sqrtf(fmaxf(e1, 1e-6f));
  float den = frn_add(fmaxf(aM, am), 1e-6f);
  axes_out[p] = make_float2(fmaxf(frn_div(aM, den), 0.2f),
                            fmaxf(frn_div(am, den), 0.2f));

  size_t rowb = (size_t)p * 5;
#pragma unroll
  for (int k = 0; k < 5; k++) {
    float l0 = frn_add(frn_mul(rx[k], v00), frn_mul(ry[k], v10));
    float l1 = frn_add(frn_mul(rx[k], v01), frn_mul(ry[k], v11));
    lcct2[rowb + k] = make_float2(l0, l1);
  }
}

// ---------------------------------------------------------------------------
// Fused layer1+layer2: out[n][m] = relu(lb2[n] + sum_k relu(h1[k][m]) * w2..)
// where h1[k][m] = fmaf(l.y, lw1t[2k+1], fmaf(l.x, lw1t[2k], lb1[k])) is
// computed into the A-tile LDS from lcct2 (no h1 round-trip through HBM).
// MB=NB=128, KB=16, KTILES=4, Kstr(w)=64.
// ---------------------------------------------------------------------------
__global__ __launch_bounds__(256, 3) void gemm_l2(
    const float2* __restrict__ lcct2, const float* __restrict__ lw1t,
    const float* __restrict__ lb1,
    const float* __restrict__ wt, const float* __restrict__ bias,
    float* __restrict__ out_t, int M) {
  __shared__ float alds[16 * 128];
  __shared__ float wlds[16 * 128];
  __shared__ float w1s[192];  // [0..127]=lw1t (64 pairs), [128..191]=lb1
  int t = threadIdx.x;
  int m0 = blockIdx.x * 128;
  if (t < 192) w1s[t] = (t < 128) ? lw1t[t] : lb1[t - 128];
  int mloc = t & 127;
  int kbase = t >> 7;  // 0 or 1 (wave-uniform)
  float2 lme = lcct2[m0 + mloc];
  int tm = t & 15;
  int tn = t >> 4;
  float acc[8][8];
#pragma unroll
  for (int j = 0; j < 8; j++) {
    float b = bias[tn * 8 + j];
#pragma unroll
    for (int i = 0; i < 8; i++) acc[j][i] = b;
  }
  for (int kt = 0; kt < 4; kt++) {
    int k0 = kt * 16;
    __syncthreads();
    // A-stage: compute h1 tile in place of a global load.
#pragma unroll
    for (int pp = 0; pp < 8; pp++) {
      int kk = pp * 2 + kbase;
      int k = k0 + kk;
      float h = fmaf(lme.y, w1s[2 * k + 1], fmaf(lme.x, w1s[2 * k], w1s[128 + k]));
      alds[kk * 128 + mloc] = fmaxf(h, 0.f);
    }
    // W-stage (WPASS = 2, Kstr = 64)
#pragma unroll
    for (int pp = 0; pp < 2; pp++) {
      int e = pp * 256 + t;
      int n = e >> 2;
      int kc = e & 3;
      float4 v = *(const float4*)(wt + (size_t)n * 64 + k0 + kc * 4);
      wlds[(kc * 4 + 0) * 128 + n] = v.x;
      wlds[(kc * 4 + 1) * 128 + n] = v.y;
      wlds[(kc * 4 + 2) * 128 + n] = v.z;
      wlds[(kc * 4 + 3) * 128 + n] = v.w;
    }
    __syncthreads();
#pragma unroll
    for (int kk = 0; kk < 16; kk++) {
      float af[8], wf[8];
      *(float4*)(af)     = *(const float4*)(alds + kk * 128 + tm * 8);
      *(float4*)(af + 4) = *(const float4*)(alds + kk * 128 + tm * 8 + 4);
      *(float4*)(wf)     = *(const float4*)(wlds + kk * 128 + tn * 8);
      *(float4*)(wf + 4) = *(const float4*)(wlds + kk * 128 + tn * 8 + 4);
#pragma unroll
      for (int j = 0; j < 8; j++)
#pragma unroll
        for (int i = 0; i < 8; i++)
          acc[j][i] = fmaf(af[i], wf[j], acc[j][i]);
    }
  }
#pragma unroll
  for (int j = 0; j < 8; j++) {
    int n = tn * 8 + j;
    float4 o0, o1;
    o0.x = fmaxf(acc[j][0], 0.f); o0.y = fmaxf(acc[j][1], 0.f);
    o0.z = fmaxf(acc[j][2], 0.f); o0.w = fmaxf(acc[j][3], 0.f);
    o1.x = fmaxf(acc[j][4], 0.f); o1.y = fmaxf(acc[j][5], 0.f);
    o1.z = fmaxf(acc[j][6], 0.f); o1.w = fmaxf(acc[j][7], 0.f);
    float* dst = out_t + (size_t)n * M + m0 + tm * 8;
    *(float4*)(dst) = o0;
    *(float4*)(dst + 4) = o1;
  }
}

// ---------------------------------------------------------------------------
// Fused layer3 + maxpool: M-tile = 320 rows = 64 whole points (K=5), so the
// per-point max over 5 rows never crosses a block boundary. 512 threads:
// thread = (pt, ng) owns one point's 5 rows x 8 outputs (acc[5][8]).
// Writes lftx rows 2..65 directly; h3 never touches HBM.
// ---------------------------------------------------------------------------
__global__ __launch_bounds__(512, 4) void gemm_l3max(
    const float* __restrict__ h2, const float* __restrict__ wt,
    const float* __restrict__ bias, float* __restrict__ lftx) {
  __shared__ float alds[16 * 320];  // 20 KB
  __shared__ float wlds[16 * 64];   // 4 KB
  int t = threadIdx.x;
  int m0 = blockIdx.x * 320;
  int pt = t & 63;
  int ng = t >> 6;  // 0..7 (wave-uniform)
  float acc[5][8];
#pragma unroll
  for (int j = 0; j < 8; j++) {
    float b = bias[ng * 8 + j];
#pragma unroll
    for (int r = 0; r < 5; r++) acc[r][j] = b;
  }
  for (int kt = 0; kt < 8; kt++) {
    int k0 = kt * 16;
    __syncthreads();
    // A stage: 16 k x 320 m = 1280 float4 (waves 0-3 do 3 passes, 4-7 do 2).
    for (int e = t; e < 1280; e += 512) {
      int kk = e / 80;
      int m4 = e - kk * 80;
      float4 v = *(const float4*)(h2 + (size_t)(k0 + kk) * ROWS + m0 + m4 * 4);
      *(float4*)(alds + kk * 320 + m4 * 4) = v;
    }
    // W stage: 16 k x 64 n = 256 float4 (threads 0..255), Kstr=128.
    if (t < 256) {
      int n = t >> 2, kc = t & 3;
      float4 v = *(const float4*)(wt + (size_t)n * 128 + k0 + kc * 4);
      wlds[(kc * 4 + 0) * 64 + n] = v.x;
      wlds[(kc * 4 + 1) * 64 + n] = v.y;
      wlds[(kc * 4 + 2) * 64 + n] = v.z;
      wlds[(kc * 4 + 3) * 64 + n] = v.w;
    }
    __syncthreads();
#pragma unroll
    for (int kk = 0; kk < 16; kk++) {
      float af[5], wf[8];
#pragma unroll
      for (int r = 0; r < 5; r++) af[r] = alds[kk * 320 + pt * 5 + r];
      *(float4*)(wf)     = *(const float4*)(wlds + kk * 64 + ng * 8);
      *(float4*)(wf + 4) = *(const float4*)(wlds + kk * 64 + ng * 8 + 4);
#pragma unroll
      for (int r = 0; r < 5; r++)
#pragma unroll
        for (int j = 0; j < 8; j++)
          acc[r][j] = fmaf(af[r], wf[j], acc[r][j]);
    }
  }
  int p = blockIdx.x * 64 + pt;
#pragma unroll
  for (int j = 0; j < 8; j++) {
    float r0 = fmaxf(acc[0][j], 0.f), r1 = fmaxf(acc[1][j], 0.f);
    float r2 = fmaxf(acc[2][j], 0.f), r3 = fmaxf(acc[3][j], 0.f);
    float r4 = fmaxf(acc[4][j], 0.f);
    float m = fmaxf(fmaxf(fmaxf(r0, r1), fmaxf(r2, r3)), r4);
    lftx[(size_t)(ng * 8 + j + 2) * PTS + p] = m;
  }
}

// ---------------------------------------------------------------------------
// Fully fused head v2: layer 1 (c1/t1) -> a1 tile in LDS -> layer 2 (c2/t2)
// -> direct row-major store into d_out. 512 blocks (bid<256 = cls chain,
// else topo), 512 threads, thread tile 8n x 4m (acc[8][4] = 32 VGPR) with
// __launch_bounds__(512,4) -> VGPR<=128 -> 4 waves/SIMD; LDS 80 KB -> 2
// blocks/CU -> 16 waves/CU. fmaf chains identical to the unfused pair.
// ---------------------------------------------------------------------------
__global__ __launch_bounds__(512, 4) void gemm_head(
    const float* __restrict__ lftx, const float* __restrict__ wtbase,
    const float* __restrict__ cb1, const float* __restrict__ tb1,
    const float* __restrict__ cb2, const float* __restrict__ tb2,
    float* __restrict__ outbase) {
  __shared__ float a1lds[128 * 128];  // 64 KB, [k][m]
  __shared__ float alds[16 * 128];    // 8 KB
  __shared__ float wlds[16 * 128];    // 8 KB
  int bid = blockIdx.x;
  bool isC = bid < 256;
  const float* in_t = isC ? lftx : (lftx + 2 * PTS);
  const float* w1   = isC ? (wtbase + 16512) : (wtbase + 43136);
  const float* b1   = isC ? cb1 : tb1;
  const float* w2   = isC ? (wtbase + 26752) : (wtbase + 51328);
  const float* b2   = isC ? cb2 : tb2;
  float* out        = isC ? outbase : (outbase + 4194304);
  int Kstr = isC ? 80 : 64;
  int KT   = isC ? 5 : 4;
  int m0 = (bid & 255) * 128;
  int t = threadIdx.x;
  int tm2 = t & 31;   // m-group of 4: cols tm2*4 .. tm2*4+3
  int tnn = t >> 5;   // 0..15: rows n = tnn*8 .. tnn*8+7
  int skk = t >> 5, sm4 = t & 31;   // A stage: [kk][m4*4]
  int swn = t >> 2, swk = t & 3;    // W stage: [n][kc*4]
  float acc[8][4];

  // ---------------- layer 1 ----------------
#pragma unroll
  for (int j = 0; j < 8; j++) {
    float b = b1[tnn * 8 + j];
#pragma unroll
    for (int i = 0; i < 4; i++) acc[j][i] = b;
  }
  for (int kt = 0; kt < KT; kt++) {
    int k0 = kt * 16;
    __syncthreads();
    {
      float4 v = *(const float4*)(in_t + (size_t)(k0 + skk) * PTS + m0 + sm4 * 4);
      *(float4*)(alds + skk * 128 + sm4 * 4) = v;
    }
    {
      float4 v = *(const float4*)(w1 + (size_t)swn * Kstr + k0 + swk * 4);
      wlds[(swk * 4 + 0) * 128 + swn] = v.x;
      wlds[(swk * 4 + 1) * 128 + swn] = v.y;
      wlds[(swk * 4 + 2) * 128 + swn] = v.z;
      wlds[(swk * 4 + 3) * 128 + swn] = v.w;
    }
    __syncthreads();
#pragma unroll
    for (int kk = 0; kk < 16; kk++) {
      float af[4], wf[8];
      *(float4*)(af)     = *(const float4*)(alds + kk * 128 + tm2 * 4);
      *(float4*)(wf)     = *(const float4*)(wlds + kk * 128 + tnn * 8);
      *(float4*)(wf + 4) = *(const float4*)(wlds + kk * 128 + tnn * 8 + 4);
#pragma unroll
      for (int j = 0; j < 8; j++)
#pragma unroll
        for (int i = 0; i < 4; i++)
          acc[j][i] = fmaf(af[i], wf[j], acc[j][i]);
    }
  }
  // relu(a1) -> LDS [n][m]
#pragma unroll
  for (int j = 0; j < 8; j++) {
    int n = tnn * 8 + j;
    float4 o;
    o.x = fmaxf(acc[j][0], 0.f); o.y = fmaxf(acc[j][1], 0.f);
    o.z = fmaxf(acc[j][2], 0.f); o.w = fmaxf(acc[j][3], 0.f);
    *(float4*)(a1lds + n * 128 + tm2 * 4) = o;
  }

  // ---------------- layer 2 ----------------
#pragma unroll
  for (int j = 0; j < 8; j++) {
    float b = b2[tnn * 8 + j];
#pragma unroll
    for (int i = 0; i < 4; i++) acc[j][i] = b;
  }
  for (int kt = 0; kt < 8; kt++) {
    int k0 = kt * 16;
    __syncthreads();  // first iter: covers a1lds writes; later: wlds reuse
    {
      float4 v = *(const float4*)(w2 + (size_t)swn * 128 + k0 + swk * 4);
      wlds[(swk * 4 + 0) * 128 + swn] = v.x;
      wlds[(swk * 4 + 1) * 128 + swn] = v.y;
      wlds[(swk * 4 + 2) * 128 + swn] = v.z;
      wlds[(swk * 4 + 3) * 128 + swn] = v.w;
    }
    __syncthreads();
#pragma unroll
    for (int kk = 0; kk < 16; kk++) {
      float af[4], wf[8];
      *(float4*)(af)     = *(const float4*)(a1lds + (k0 + kk) * 128 + tm2 * 4);
      *(float4*)(wf)     = *(const float4*)(wlds + kk * 128 + tnn * 8);
      *(float4*)(wf + 4) = *(const float4*)(wlds + kk * 128 + tnn * 8 + 4);
#pragma unroll
      for (int j = 0; j < 8; j++)
#pragma unroll
        for (int i = 0; i < 4; i++)
          acc[j][i] = fmaf(af[i], wf[j], acc[j][i]);
    }
  }
  // Row-major epilogue: per i, store 8 contiguous n at out[m*128 + tnn*8].
#pragma unroll
  for (int i = 0; i < 4; i++) {
    int m = m0 + tm2 * 4 + i;
    float4 q0, q1;
    q0.x = fmaxf(acc[0][i], 0.f); q0.y = fmaxf(acc[1][i], 0.f);
    q0.z = fmaxf(acc[2][i], 0.f); q0.w = fmaxf(acc[3][i], 0.f);
    q1.x = fmaxf(acc[4][i], 0.f); q1.y = fmaxf(acc[5][i], 0.f);
    q1.z = fmaxf(acc[6][i], 0.f); q1.w = fmaxf(acc[7][i], 0.f);
    float* dst = out + (size_t)m * 128 + tnn * 8;
    *(float4*)(dst) = q0;
    *(float4*)(dst + 4) = q1;
  }
}

// ---------------------------------------------------------------------------
extern "C" void kernel_launch(void* const* d_in, const int* in_sizes, int n_in,
                              void* d_out, int out_size, void* d_ws, size_t ws_size,
                              hipStream_t stream) {
  const float* x   = (const float*)d_in[0];
  const float* lb1 = (const float*)d_in[2];
  const float* lb2 = (const float*)d_in[4];
  const float* lb3 = (const float*)d_in[6];
  const float* cb1 = (const float*)d_in[8];
  const float* cb2 = (const float*)d_in[10];
  const float* tb1 = (const float*)d_in[12];
  const float* tb2 = (const float*)d_in[14];

  float* out = (float*)d_out;
  float* angle_out = out + 8388608;
  float* axes_out  = out + 8421376;

  // Workspace (floats), lifetime-overlapped:
  //   wt    [67712]
  //   R1    [10485760]  ipart (knn->merge, 1M u32 used)
  //   R2    [10485760]  (free)
  //   R3    [20971520]  h2 (l2->l3max)
  //   lftx  [2621440]
  //   lcct2 [327680]    interleaved (l0,l1) per row
  float* W = (float*)d_ws;
  float* wt    = W;
  float* R1    = W + 67712;
  float* R2    = R1 + 10485760;
  float* R3    = R2 + 10485760;
  float* lftx  = R3 + 20971520;
  float* lcct2 = lftx + 2621440;
  unsigned int* ipart = (unsigned int*)R1;
  float* h2    = R3;
  (void)R2;

  prep_w<<<7, 256, 0, stream>>>((const float*)d_in[1], (const float*)d_in[3], (const float*)d_in[5],
                                (const float*)d_in[7], (const float*)d_in[9],
                                (const float*)d_in[11], (const float*)d_in[13], wt);
  knn_scan<<<512, 256, 0, stream>>>(x, ipart);
  merge_geom<<<256, 128, 0, stream>>>(x, ipart, (float2*)lcct2, angle_out, (float2*)axes_out, lftx);

  gemm_l2<<<ROWS / 128, 256, 0, stream>>>((const float2*)lcct2, wt + 0, lb1,
                                          wt + 128, lb2, h2, ROWS);
  gemm_l3max<<<PTS / 64, 512, 0, stream>>>(h2, wt + 8320, lb3, lftx);

  gemm_head<<<512, 512, 0, stream>>>(lftx, wt, cb1, tb1, cb2, tb2, out);
}

// Round 15
// 284.325 us; speedup vs baseline: 1.0433x; 1.0433x over previous
//
#include <hip/hip_runtime.h>
#include <math.h>

#pragma clang fp contract(off)

#define NPTS 4096
#define PTS  32768
#define ROWS 163840   // PTS * 5
#define QN   8        // candidate slices per batch
#define QLEN 512      // NPTS / QN
#define SLOTS 8       // packed top-k slots per slice (and global survivors)

// LAPACK single-precision machine constants (gfortran/IEEE):
#define EPS_L   5.9604644775390625e-8f    // 2^-24  SLAMCH('E')
#define EPS2_L  3.5527136788005009e-15f   // 2^-48
#define SAFMIN_L 1.1754943508222875e-38f  // 2^-126

// Round-to-nearest, non-contractible f32 ops (file pragma disables fusion).
__device__ __forceinline__ float frn_mul(float a, float b) { float r = a * b; return r; }
__device__ __forceinline__ float frn_add(float a, float b) { float r = a + b; return r; }
__device__ __forceinline__ float frn_sub(float a, float b) { float r = a - b; return r; }
__device__ __forceinline__ float frn_div(float a, float b) { float r = a / b; return r; }

__device__ __forceinline__ float ref_sq(float x0, float x1) {
  return frn_add(frn_mul(x0, x0), frn_mul(x1, x1));
}
// dist_sq[n,m] = fl( fl(sq_n + sq_m) - 2*dot ), dot = fma(ny*my, fl(nx*mx)).
__device__ __forceinline__ float ref_key(float nx, float ny, float sqn,
                                         float mx, float my, float sqm) {
  float dot = fmaf(ny, my, frn_mul(nx, mx));
  float s = frn_add(sqn, sqm);
  return fmaf(-2.0f, dot, s);
}

// ---------------------------------------------------------------------------
// Weight transpose prep, zero-padded K stride: wt[j*Kp + i] = (i<K)? w[i*N+j]:0
// ---------------------------------------------------------------------------
__global__ __launch_bounds__(256) void prep_w(
    const float* __restrict__ lw1, const float* __restrict__ lw2, const float* __restrict__ lw3,
    const float* __restrict__ cw1, const float* __restrict__ cw2,
    const float* __restrict__ tw1, const float* __restrict__ tw2,
    float* __restrict__ wt) {
  const int Ks[7]   = {2, 64, 128, 66, 128, 64, 128};
  const int Kp[7]   = {2, 64, 128, 80, 128, 64, 128};
  const int Ns[7]   = {64, 128, 64, 128, 128, 128, 128};
  const int offs[7] = {0, 128, 8320, 16512, 26752, 43136, 51328};
  const float* srcs[7] = {lw1, lw2, lw3, cw1, cw2, tw1, tw2};
  int b = blockIdx.x;
  const float* src = srcs[b];
  float* dst = wt + offs[b];
  int K = Ks[b], KP = Kp[b], N = Ns[b];
  for (int e = threadIdx.x; e < KP * N; e += 256) {
    int j = e / KP, i = e - j * KP;
    dst[e] = (i < K) ? src[i * N + j] : 0.0f;
  }
}

// ---------------------------------------------------------------------------
// kNN scan (brute force), R4-measured best shape: 1024 blocks = 128
// point-groups of 256 x 8 candidate-slices of 512; 20 KB LDS.
// Threshold-filtered top-8, unroll-4, unconditional buffered append
// (failing write lands in slot cnt; only promoted when a passing value
// overwrites it). Flush-check every 4 candidates, cnt>=13 (start-of-group
// cnt<=12, +4 appends -> slots <= 15).
// Packed value = (bits(dist)&0xFFFFF000)|idx (dist >= 0 u32-monotone).
// Monotone threshold T => no true top-8 element dropped (values distinct by
// idx); exact ref-key re-rank happens in merge_geom.
// ---------------------------------------------------------------------------
__device__ __forceinline__ void cand_step(float mex, float mey, float cx, float cy,
                                          unsigned int idx, unsigned int T,
                                          unsigned int* sbuf, int t,
                                          unsigned int& cnt) {
  float dx = mex - cx, dy = mey - cy;
  float dist = fmaf(dy, dy, dx * dx);
  unsigned int v = (__float_as_uint(dist) & 0xFFFFF000u) | idx;
  sbuf[cnt * 256 + t] = v;
  cnt += (v < T) ? 1u : 0u;
}

__global__ __launch_bounds__(256) void knn_scan(const float* __restrict__ x,
                                                unsigned int* __restrict__ ipart) {
  __shared__ float2 cand[QLEN];            // 4 KB
  __shared__ unsigned int sbuf[16 * 256];  // 16 KB survivor buffer
  int bx = blockIdx.x;
  int q = bx & (QN - 1);
  int pg = bx >> 3;              // 0..127 point-groups of 256
  int batch = pg >> 4;           // 16 groups per batch
  const float* xb = x + (size_t)batch * NPTS * 2;
  int c0 = q * QLEN;
  for (int i = threadIdx.x; i < QLEN; i += 256)
    cand[i] = ((const float2*)xb)[c0 + i];
  __syncthreads();
  int t = threadIdx.x;
  int p = pg * 256 + t;
  float2 me = ((const float2*)x)[p];
  unsigned int d[SLOTS];
#pragma unroll
  for (int s = 0; s < SLOTS; s++) d[s] = 0xFFFFFFFFu;
  unsigned int T = 0xFFFFFFFFu;
  unsigned int cnt = 0;
  for (int mm = 0; mm < QLEN / 4; mm++) {
    float4 c01 = ((const float4*)cand)[2 * mm];
    float4 c23 = ((const float4*)cand)[2 * mm + 1];
    unsigned int idx0 = (unsigned int)(c0 + 4 * mm);
    cand_step(me.x, me.y, c01.x, c01.y, idx0 + 0u, T, sbuf, t, cnt);
    cand_step(me.x, me.y, c01.z, c01.w, idx0 + 1u, T, sbuf, t, cnt);
    cand_step(me.x, me.y, c23.x, c23.y, idx0 + 2u, T, sbuf, t, cnt);
    cand_step(me.x, me.y, c23.z, c23.w, idx0 + 3u, T, sbuf, t, cnt);
    if (__any((int)(cnt >= 13u))) {
#pragma unroll
      for (int j = 0; j < 16; j++) {
        unsigned int u = ((unsigned)j < cnt) ? sbuf[j * 256 + t] : 0xFFFFFFFFu;
#pragma unroll
        for (int s = 0; s < SLOTS; s++) {
          unsigned int lo = min(u, d[s]);
          unsigned int hi = max(u, d[s]);
          d[s] = lo; u = hi;
        }
      }
      cnt = 0;
      T = d[SLOTS - 1];
    }
  }
  // final flush of residual buffer entries
#pragma unroll
  for (int j = 0; j < 16; j++) {
    unsigned int u = ((unsigned)j < cnt) ? sbuf[j * 256 + t] : 0xFFFFFFFFu;
#pragma unroll
    for (int s = 0; s < SLOTS; s++) {
      unsigned int lo = min(u, d[s]);
      unsigned int hi = max(u, d[s]);
      d[s] = lo; u = hi;
    }
  }
#pragma unroll
  for (int s = 0; s < SLOTS; s++)
    ipart[((size_t)(q * SLOTS + s)) * PTS + p] = d[s];
}

#define CAS(a, b) { unsigned int _l = min(a, b), _h = max(a, b); a = _l; b = _h; }

// ---------------------------------------------------------------------------
// Merge + geometry. Tree-merges the QN=8 sorted slice-lists (bitonic
// merge-of-two-sorted-8s, proven R11-R13) -> packed top-8 -> exact (f32 ref
// key, idx) lex re-rank -> reference top-5 -> covariance -> ssteqr/SLAEV2
// replica -> angle/axes + interleaved lcc (float2). Also writes the
// x-passthrough rows (0,1) of lftx and zero-fills padding rows 66..79.
// 256 blocks x 128 threads.
// ---------------------------------------------------------------------------
__global__ __launch_bounds__(128) void merge_geom(const float* __restrict__ x,
    const unsigned int* __restrict__ ipart,
    float2* __restrict__ lcct2,
    float* __restrict__ angle_out, float2* __restrict__ axes_out,
    float* __restrict__ lftx) {
  int p = blockIdx.x * 128 + threadIdx.x;
  int batch = p >> 12;
  const float2* xb = (const float2*)(x + (size_t)batch * NPTS * 2);
  float2 me = ((const float2*)x)[p];
  lftx[p] = me.x;
  lftx[PTS + p] = me.y;
#pragma unroll
  for (int r = 66; r < 80; r++) lftx[(size_t)r * PTS + p] = 0.0f;
  float sqn = ref_sq(me.x, me.y);

  // Gather: tree-merge 8 sorted lists, keeping the 8 smallest (all values
  // distinct by idx; each merge is exact).
  unsigned int g[SLOTS];
#pragma unroll
  for (int s = 0; s < SLOTS; s++) g[s] = ipart[(size_t)s * PTS + p];
  for (int qs = 1; qs < QN; qs++) {
    unsigned int B[SLOTS];
#pragma unroll
    for (int s = 0; s < SLOTS; s++) B[s] = ipart[(size_t)(qs * SLOTS + s) * PTS + p];
    unsigned int w[SLOTS];
#pragma unroll
    for (int s = 0; s < SLOTS; s++) w[s] = min(g[s], B[SLOTS - 1 - s]);
    // bitonic clean of 8 (ascending): stages 4, 2, 1
    CAS(w[0], w[4]); CAS(w[1], w[5]); CAS(w[2], w[6]); CAS(w[3], w[7]);
    CAS(w[0], w[2]); CAS(w[1], w[3]); CAS(w[4], w[6]); CAS(w[5], w[7]);
    CAS(w[0], w[1]); CAS(w[2], w[3]); CAS(w[4], w[5]); CAS(w[6], w[7]);
#pragma unroll
    for (int s = 0; s < SLOTS; s++) g[s] = w[s];
  }

  float dk[5]; int id[5];
#pragma unroll
  for (int s = 0; s < 5; s++) { dk[s] = 3.0e38f; id[s] = 0x7fffffff; }
#pragma unroll
  for (int s8 = 0; s8 < SLOTS; s8++) {
    int ci = (int)(g[s8] & 0xFFFu);
    float2 c = xb[ci];
    float key = ref_key(me.x, me.y, sqn, c.x, c.y, ref_sq(c.x, c.y));
    float v = key; int vi = ci;
#pragma unroll
    for (int s = 0; s < 5; s++) {
      bool lt = (v < dk[s]) || (v == dk[s] && vi < id[s]);
      float tv = dk[s]; int ti = id[s];
      if (lt) { dk[s] = v; id[s] = vi; v = tv; vi = ti; }
    }
  }
  float rx[5], ry[5];
  float sx = 0.f, sy = 0.f;
#pragma unroll
  for (int k = 0; k < 5; k++) {
    float2 nb = xb[id[k]];
    rx[k] = frn_sub(nb.x, me.x); ry[k] = frn_sub(nb.y, me.y);
    sx = frn_add(sx, rx[k]); sy = frn_add(sy, ry[k]);
  }
  float mx = frn_div(sx, 5.0f), my = frn_div(sy, 5.0f);
  float c00 = 0.f, c01 = 0.f, c11 = 0.f;
#pragma unroll
  for (int k = 0; k < 5; k++) {
    rx[k] = frn_sub(rx[k], mx); ry[k] = frn_sub(ry[k], my);
    c00 = frn_add(c00, frn_mul(rx[k], rx[k]));
    c01 = frn_add(c01, frn_mul(rx[k], ry[k]));
    c11 = frn_add(c11, frn_mul(ry[k], ry[k]));
  }
  c00 = frn_div(c00, 4.0f); c01 = frn_div(c01, 4.0f); c11 = frn_div(c11, 4.0f);
  float A = frn_add(c00, 1e-6f), Bv = c01, C = frn_add(c11, 1e-6f);

  // ---- ssteqr 2x2 replica ----
  float absA = fabsf(A), absC = fabsf(C), absB = fabsf(Bv);
  float thr = frn_mul(frn_mul(sqrtf(absA), sqrtf(absC)), EPS_L);
  bool diag = (absB == 0.f) || (absB <= thr);
  if (!diag) {
    bool qr = (absC < absA);
    float b2 = frn_mul(absB, absB);
    float t = qr ? frn_add(frn_mul(frn_mul(EPS2_L, absC), absA), SAFMIN_L)
                 : frn_add(frn_mul(frn_mul(EPS2_L, absA), absC), SAFMIN_L);
    if (b2 <= t) diag = true;
  }
  float e1, e2, v00, v10, v01, v11;
  if (diag) {
    if (C < A) { e1 = C; e2 = A; v00 = 0.f; v10 = 1.f; v01 = 1.f; v11 = 0.f; }
    else       { e1 = A; e2 = C; v00 = 1.f; v10 = 0.f; v01 = 0.f; v11 = 1.f; }
  } else {
    // ---- SLAEV2 replica ----
    float sm = frn_add(A, C), df = frn_sub(A, C);
    float adf = fabsf(df), tb = frn_add(Bv, Bv), ab = fabsf(tb);
    float rt;
    if (adf > ab) {
      float r = frn_div(ab, adf);
      rt = frn_mul(adf, sqrtf(frn_add(1.0f, frn_mul(r, r))));
    } else if (adf < ab) {
      float r = frn_div(adf, ab);
      rt = frn_mul(ab, sqrtf(frn_add(1.0f, frn_mul(r, r))));
    } else {
      rt = frn_mul(ab, sqrtf(2.0f));
    }
    float acmx, acmn;
    if (absA > absC) { acmx = A; acmn = C; } else { acmx = C; acmn = A; }
    float rt1, rt2; int sgn1;
    if (sm < 0.f) {
      rt1 = frn_mul(0.5f, frn_sub(sm, rt)); sgn1 = -1;
      rt2 = frn_sub(frn_mul(frn_div(acmx, rt1), acmn), frn_mul(frn_div(Bv, rt1), Bv));
    } else if (sm > 0.f) {
      rt1 = frn_mul(0.5f, frn_add(sm, rt)); sgn1 = 1;
      rt2 = frn_sub(frn_mul(frn_div(acmx, rt1), acmn), frn_mul(frn_div(Bv, rt1), Bv));
    } else {
      rt1 = frn_mul(0.5f, rt); rt2 = frn_mul(-0.5f, rt); sgn1 = 1;
    }
    float cs, cs1, sn1; int sgn2;
    if (df >= 0.f) { cs = frn_add(df, rt); sgn2 = 1; }
    else           { cs = frn_sub(df, rt); sgn2 = -1; }
    float acs = fabsf(cs);
    if (acs > ab) {
      float ct = frn_div(-tb, cs);
      sn1 = frn_div(1.0f, sqrtf(frn_add(1.0f, frn_mul(ct, ct))));
      cs1 = frn_mul(ct, sn1);
    } else {
      if (ab == 0.f) { cs1 = 1.0f; sn1 = 0.0f; }
      else {
        float tn = frn_div(-cs, tb);
        cs1 = frn_div(1.0f, sqrtf(frn_add(1.0f, frn_mul(tn, tn))));
        sn1 = frn_mul(tn, cs1);
      }
    }
    if (sgn1 == sgn2) { float t = cs1; cs1 = -sn1; sn1 = t; }
    if (rt2 < rt1) { e1 = rt2; e2 = rt1; v00 = -sn1; v10 = cs1; v01 = cs1;  v11 = sn1; }
    else           { e1 = rt1; e2 = rt2; v00 = cs1;  v10 = sn1; v01 = -sn1; v11 = cs1; }
  }

  angle_out[p] = atan2f(v11, v01);
  float aM = sqrtf(fmaxf(e2, 1e-6f));
  float am = sqrtf(fmaxf(e1, 1e-6f));
  float den = frn_add(fmaxf(aM, am), 1e-6f);
  axes_out[p] = make_float2(fmaxf(frn_div(aM, den), 0.2f),
                            fmaxf(frn_div(am, den), 0.2f));

  size_t rowb = (size_t)p * 5;
#pragma unroll
  for (int k = 0; k < 5; k++) {
    float l0 = frn_add(frn_mul(rx[k], v00), frn_mul(ry[k], v10));
    float l1 = frn_add(frn_mul(rx[k], v01), frn_mul(ry[k], v11));
    lcct2[rowb + k] = make_float2(l0, l1);
  }
}

// ---------------------------------------------------------------------------
// Fused layer1+layer2: out[n][m] = relu(lb2[n] + sum_k relu(h1[k][m]) * w2..)
// where h1[k][m] = fmaf(l.y, lw1t[2k+1], fmaf(l.x, lw1t[2k], lb1[k])) is
// computed into the A-tile LDS from lcct2 (no h1 round-trip through HBM).
// MB=NB=128, KB=16, KTILES=4, Kstr(w)=64.
// ---------------------------------------------------------------------------
__global__ __launch_bounds__(256, 3) void gemm_l2(
    const float2* __restrict__ lcct2, const float* __restrict__ lw1t,
    const float* __restrict__ lb1,
    const float* __restrict__ wt, const float* __restrict__ bias,
    float* __restrict__ out_t, int M) {
  __shared__ float alds[16 * 128];
  __shared__ float wlds[16 * 128];
  __shared__ float w1s[192];  // [0..127]=lw1t (64 pairs), [128..191]=lb1
  int t = threadIdx.x;
  int m0 = blockIdx.x * 128;
  if (t < 192) w1s[t] = (t < 128) ? lw1t[t] : lb1[t - 128];
  int mloc = t & 127;
  int kbase = t >> 7;  // 0 or 1 (wave-uniform)
  float2 lme = lcct2[m0 + mloc];
  int tm = t & 15;
  int tn = t >> 4;
  float acc[8][8];
#pragma unroll
  for (int j = 0; j < 8; j++) {
    float b = bias[tn * 8 + j];
#pragma unroll
    for (int i = 0; i < 8; i++) acc[j][i] = b;
  }
  for (int kt = 0; kt < 4; kt++) {
    int k0 = kt * 16;
    __syncthreads();
    // A-stage: compute h1 tile in place of a global load.
#pragma unroll
    for (int pp = 0; pp < 8; pp++) {
      int kk = pp * 2 + kbase;
      int k = k0 + kk;
      float h = fmaf(lme.y, w1s[2 * k + 1], fmaf(lme.x, w1s[2 * k], w1s[128 + k]));
      alds[kk * 128 + mloc] = fmaxf(h, 0.f);
    }
    // W-stage (WPASS = 2, Kstr = 64)
#pragma unroll
    for (int pp = 0; pp < 2; pp++) {
      int e = pp * 256 + t;
      int n = e >> 2;
      int kc = e & 3;
      float4 v = *(const float4*)(wt + (size_t)n * 64 + k0 + kc * 4);
      wlds[(kc * 4 + 0) * 128 + n] = v.x;
      wlds[(kc * 4 + 1) * 128 + n] = v.y;
      wlds[(kc * 4 + 2) * 128 + n] = v.z;
      wlds[(kc * 4 + 3) * 128 + n] = v.w;
    }
    __syncthreads();
#pragma unroll
    for (int kk = 0; kk < 16; kk++) {
      float af[8], wf[8];
      *(float4*)(af)     = *(const float4*)(alds + kk * 128 + tm * 8);
      *(float4*)(af + 4) = *(const float4*)(alds + kk * 128 + tm * 8 + 4);
      *(float4*)(wf)     = *(const float4*)(wlds + kk * 128 + tn * 8);
      *(float4*)(wf + 4) = *(const float4*)(wlds + kk * 128 + tn * 8 + 4);
#pragma unroll
      for (int j = 0; j < 8; j++)
#pragma unroll
        for (int i = 0; i < 8; i++)
          acc[j][i] = fmaf(af[i], wf[j], acc[j][i]);
    }
  }
#pragma unroll
  for (int j = 0; j < 8; j++) {
    int n = tn * 8 + j;
    float4 o0, o1;
    o0.x = fmaxf(acc[j][0], 0.f); o0.y = fmaxf(acc[j][1], 0.f);
    o0.z = fmaxf(acc[j][2], 0.f); o0.w = fmaxf(acc[j][3], 0.f);
    o1.x = fmaxf(acc[j][4], 0.f); o1.y = fmaxf(acc[j][5], 0.f);
    o1.z = fmaxf(acc[j][6], 0.f); o1.w = fmaxf(acc[j][7], 0.f);
    float* dst = out_t + (size_t)n * M + m0 + tm * 8;
    *(float4*)(dst) = o0;
    *(float4*)(dst + 4) = o1;
  }
}

// ---------------------------------------------------------------------------
// Fused layer3 + maxpool: M-tile = 320 rows = 64 whole points (K=5), so the
// per-point max over 5 rows never crosses a block boundary. 512 threads:
// thread = (pt, ng) owns one point's 5 rows x 8 outputs (acc[5][8]).
// Writes lftx rows 2..65 directly; h3 never touches HBM.
// ---------------------------------------------------------------------------
__global__ __launch_bounds__(512, 4) void gemm_l3max(
    const float* __restrict__ h2, const float* __restrict__ wt,
    const float* __restrict__ bias, float* __restrict__ lftx) {
  __shared__ float alds[16 * 320];  // 20 KB
  __shared__ float wlds[16 * 64];   // 4 KB
  int t = threadIdx.x;
  int m0 = blockIdx.x * 320;
  int pt = t & 63;
  int ng = t >> 6;  // 0..7 (wave-uniform)
  float acc[5][8];
#pragma unroll
  for (int j = 0; j < 8; j++) {
    float b = bias[ng * 8 + j];
#pragma unroll
    for (int r = 0; r < 5; r++) acc[r][j] = b;
  }
  for (int kt = 0; kt < 8; kt++) {
    int k0 = kt * 16;
    __syncthreads();
    // A stage: 16 k x 320 m = 1280 float4 (waves 0-3 do 3 passes, 4-7 do 2).
    for (int e = t; e < 1280; e += 512) {
      int kk = e / 80;
      int m4 = e - kk * 80;
      float4 v = *(const float4*)(h2 + (size_t)(k0 + kk) * ROWS + m0 + m4 * 4);
      *(float4*)(alds + kk * 320 + m4 * 4) = v;
    }
    // W stage: 16 k x 64 n = 256 float4 (threads 0..255), Kstr=128.
    if (t < 256) {
      int n = t >> 2, kc = t & 3;
      float4 v = *(const float4*)(wt + (size_t)n * 128 + k0 + kc * 4);
      wlds[(kc * 4 + 0) * 64 + n] = v.x;
      wlds[(kc * 4 + 1) * 64 + n] = v.y;
      wlds[(kc * 4 + 2) * 64 + n] = v.z;
      wlds[(kc * 4 + 3) * 64 + n] = v.w;
    }
    __syncthreads();
#pragma unroll
    for (int kk = 0; kk < 16; kk++) {
      float af[5], wf[8];
#pragma unroll
      for (int r = 0; r < 5; r++) af[r] = alds[kk * 320 + pt * 5 + r];
      *(float4*)(wf)     = *(const float4*)(wlds + kk * 64 + ng * 8);
      *(float4*)(wf + 4) = *(const float4*)(wlds + kk * 64 + ng * 8 + 4);
#pragma unroll
      for (int r = 0; r < 5; r++)
#pragma unroll
        for (int j = 0; j < 8; j++)
          acc[r][j] = fmaf(af[r], wf[j], acc[r][j]);
    }
  }
  int p = blockIdx.x * 64 + pt;
#pragma unroll
  for (int j = 0; j < 8; j++) {
    float r0 = fmaxf(acc[0][j], 0.f), r1 = fmaxf(acc[1][j], 0.f);
    float r2 = fmaxf(acc[2][j], 0.f), r3 = fmaxf(acc[3][j], 0.f);
    float r4 = fmaxf(acc[4][j], 0.f);
    float m = fmaxf(fmaxf(fmaxf(r0, r1), fmaxf(r2, r3)), r4);
    lftx[(size_t)(ng * 8 + j + 2) * PTS + p] = m;
  }
}

// ---------------------------------------------------------------------------
// Fully fused head v2: layer 1 (c1/t1) -> a1 tile in LDS -> layer 2 (c2/t2)
// -> direct row-major store into d_out. 512 blocks (bid<256 = cls chain,
// else topo), 512 threads, thread tile 8n x 4m (acc[8][4] = 32 VGPR) with
// __launch_bounds__(512,4) -> VGPR<=128 -> 4 waves/SIMD; LDS 80 KB -> 2
// blocks/CU -> 16 waves/CU. fmaf chains identical to the unfused pair.
// ---------------------------------------------------------------------------
__global__ __launch_bounds__(512, 4) void gemm_head(
    const float* __restrict__ lftx, const float* __restrict__ wtbase,
    const float* __restrict__ cb1, const float* __restrict__ tb1,
    const float* __restrict__ cb2, const float* __restrict__ tb2,
    float* __restrict__ outbase) {
  __shared__ float a1lds[128 * 128];  // 64 KB, [k][m]
  __shared__ float alds[16 * 128];    // 8 KB
  __shared__ float wlds[16 * 128];    // 8 KB
  int bid = blockIdx.x;
  bool isC = bid < 256;
  const float* in_t = isC ? lftx : (lftx + 2 * PTS);
  const float* w1   = isC ? (wtbase + 16512) : (wtbase + 43136);
  const float* b1   = isC ? cb1 : tb1;
  const float* w2   = isC ? (wtbase + 26752) : (wtbase + 51328);
  const float* b2   = isC ? cb2 : tb2;
  float* out        = isC ? outbase : (outbase + 4194304);
  int Kstr = isC ? 80 : 64;
  int KT   = isC ? 5 : 4;
  int m0 = (bid & 255) * 128;
  int t = threadIdx.x;
  int tm2 = t & 31;   // m-group of 4: cols tm2*4 .. tm2*4+3
  int tnn = t >> 5;   // 0..15: rows n = tnn*8 .. tnn*8+7
  int skk = t >> 5, sm4 = t & 31;   // A stage: [kk][m4*4]
  int swn = t >> 2, swk = t & 3;    // W stage: [n][kc*4]
  float acc[8][4];

  // ---------------- layer 1 ----------------
#pragma unroll
  for (int j = 0; j < 8; j++) {
    float b = b1[tnn * 8 + j];
#pragma unroll
    for (int i = 0; i < 4; i++) acc[j][i] = b;
  }
  for (int kt = 0; kt < KT; kt++) {
    int k0 = kt * 16;
    __syncthreads();
    {
      float4 v = *(const float4*)(in_t + (size_t)(k0 + skk) * PTS + m0 + sm4 * 4);
      *(float4*)(alds + skk * 128 + sm4 * 4) = v;
    }
    {
      float4 v = *(const float4*)(w1 + (size_t)swn * Kstr + k0 + swk * 4);
      wlds[(swk * 4 + 0) * 128 + swn] = v.x;
      wlds[(swk * 4 + 1) * 128 + swn] = v.y;
      wlds[(swk * 4 + 2) * 128 + swn] = v.z;
      wlds[(swk * 4 + 3) * 128 + swn] = v.w;
    }
    __syncthreads();
#pragma unroll
    for (int kk = 0; kk < 16; kk++) {
      float af[4], wf[8];
      *(float4*)(af)     = *(const float4*)(alds + kk * 128 + tm2 * 4);
      *(float4*)(wf)     = *(const float4*)(wlds + kk * 128 + tnn * 8);
      *(float4*)(wf + 4) = *(const float4*)(wlds + kk * 128 + tnn * 8 + 4);
#pragma unroll
      for (int j = 0; j < 8; j++)
#pragma unroll
        for (int i = 0; i < 4; i++)
          acc[j][i] = fmaf(af[i], wf[j], acc[j][i]);
    }
  }
  // relu(a1) -> LDS [n][m]
#pragma unroll
  for (int j = 0; j < 8; j++) {
    int n = tnn * 8 + j;
    float4 o;
    o.x = fmaxf(acc[j][0], 0.f); o.y = fmaxf(acc[j][1], 0.f);
    o.z = fmaxf(acc[j][2], 0.f); o.w = fmaxf(acc[j][3], 0.f);
    *(float4*)(a1lds + n * 128 + tm2 * 4) = o;
  }

  // ---------------- layer 2 ----------------
#pragma unroll
  for (int j = 0; j < 8; j++) {
    float b = b2[tnn * 8 + j];
#pragma unroll
    for (int i = 0; i < 4; i++) acc[j][i] = b;
  }
  for (int kt = 0; kt < 8; kt++) {
    int k0 = kt * 16;
    __syncthreads();  // first iter: covers a1lds writes; later: wlds reuse
    {
      float4 v = *(const float4*)(w2 + (size_t)swn * 128 + k0 + swk * 4);
      wlds[(swk * 4 + 0) * 128 + swn] = v.x;
      wlds[(swk * 4 + 1) * 128 + swn] = v.y;
      wlds[(swk * 4 + 2) * 128 + swn] = v.z;
      wlds[(swk * 4 + 3) * 128 + swn] = v.w;
    }
    __syncthreads();
#pragma unroll
    for (int kk = 0; kk < 16; kk++) {
      float af[4], wf[8];
      *(float4*)(af)     = *(const float4*)(a1lds + (k0 + kk) * 128 + tm2 * 4);
      *(float4*)(wf)     = *(const float4*)(wlds + kk * 128 + tnn * 8);
      *(float4*)(wf + 4) = *(const float4*)(wlds + kk * 128 + tnn * 8 + 4);
#pragma unroll
      for (int j = 0; j < 8; j++)
#pragma unroll
        for (int i = 0; i < 4; i++)
          acc[j][i] = fmaf(af[i], wf[j], acc[j][i]);
    }
  }
  // Row-major epilogue: per i, store 8 contiguous n at out[m*128 + tnn*8].
#pragma unroll
  for (int i = 0; i < 4; i++) {
    int m = m0 + tm2 * 4 + i;
    float4 q0, q1;
    q0.x = fmaxf(acc[0][i], 0.f); q0.y = fmaxf(acc[1][i], 0.f);
    q0.z = fmaxf(acc[2][i], 0.f); q0.w = fmaxf(acc[3][i], 0.f);
    q1.x = fmaxf(acc[4][i], 0.f); q1.y = fmaxf(acc[5][i], 0.f);
    q1.z = fmaxf(acc[6][i], 0.f); q1.w = fmaxf(acc[7][i], 0.f);
    float* dst = out + (size_t)m * 128 + tnn * 8;
    *(float4*)(dst) = q0;
    *(float4*)(dst + 4) = q1;
  }
}

// ---------------------------------------------------------------------------
extern "C" void kernel_launch(void* const* d_in, const int* in_sizes, int n_in,
                              void* d_out, int out_size, void* d_ws, size_t ws_size,
                              hipStream_t stream) {
  const float* x   = (const float*)d_in[0];
  const float* lb1 = (const float*)d_in[2];
  const float* lb2 = (const float*)d_in[4];
  const float* lb3 = (const float*)d_in[6];
  const float* cb1 = (const float*)d_in[8];
  const float* cb2 = (const float*)d_in[10];
  const float* tb1 = (const float*)d_in[12];
  const float* tb2 = (const float*)d_in[14];

  float* out = (float*)d_out;
  float* angle_out = out + 8388608;
  float* axes_out  = out + 8421376;

  // Workspace (floats), lifetime-overlapped:
  //   wt    [67712]
  //   R1    [10485760]  ipart (knn->merge, 2M u32 used)
  //   R2    [10485760]  (free)
  //   R3    [20971520]  h2 (l2->l3max)
  //   lftx  [2621440]
  //   lcct2 [327680]    interleaved (l0,l1) per row
  float* W = (float*)d_ws;
  float* wt    = W;
  float* R1    = W + 67712;
  float* R2    = R1 + 10485760;
  float* R3    = R2 + 10485760;
  float* lftx  = R3 + 20971520;
  float* lcct2 = lftx + 2621440;
  unsigned int* ipart = (unsigned int*)R1;
  float* h2    = R3;
  (void)R2;

  prep_w<<<7, 256, 0, stream>>>((const float*)d_in[1], (const float*)d_in[3], (const float*)d_in[5],
                                (const float*)d_in[7], (const float*)d_in[9],
                                (const float*)d_in[11], (const float*)d_in[13], wt);
  knn_scan<<<1024, 256, 0, stream>>>(x, ipart);
  merge_geom<<<256, 128, 0, stream>>>(x, ipart, (float2*)lcct2, angle_out, (float2*)axes_out, lftx);

  gemm_l2<<<ROWS / 128, 256, 0, stream>>>((const float2*)lcct2, wt + 0, lb1,
                                          wt + 128, lb2, h2, ROWS);
  gemm_l3max<<<PTS / 64, 512, 0, stream>>>(h2, wt + 8320, lb3, lftx);

  gemm_head<<<512, 512, 0, stream>>>(lftx, wt, cb1, tb1, cb2, tb2, out);
}